// Round 1
// 169.591 us; speedup vs baseline: 1.2237x; 1.2237x over previous
//
#include <hip/hip_runtime.h>

// Problem constants: B=4, De=Do=64, T=4, H=W=128, PATCH=7, R=3
#define ATTN_OFF 4194304                 // B*Do*H*W (mem region size in floats)
// packed attn ws: [b][G=256][t][13][64] float4  = 3,407,872 float4s
#define WS_F4_COUNT 3407872ull

// ---------------------------------------------------------------------------
// K1 v2: correlation logits.
//  - 2 vertical pixels per thread (tile 32x16), 8-row shared window ->
//    ds_read_b128 per pixel drops 784 -> 448.
//  - staging: one aligned float4 global load per 4 staged floats, NO integer
//    divisions by runtime-ish constants in the hot path (only /10 magic-mul),
//    whole-vector edge predicate. Halo x padded to [-4, +36) = 40 floats,
//    LDS x-dim padded to 42 (row stride 168 dw === 8 mod 32 -> ~4-way writes).
//  - channel summation order unchanged (c = 0..63 sequential) -> numerics
//    identical to the validated version.
// ---------------------------------------------------------------------------
__global__ __launch_bounds__(256, 2) void k1_corr(
    const float* __restrict__ m_in, const float* __restrict__ q_in,
    float* __restrict__ out)
{
  const int b = blockIdx.z >> 2, t = blockIdx.z & 3;
  const int h0 = blockIdx.y * 16, w0 = blockIdx.x * 32;
  const int tid = threadIdx.x;
  const int tx = tid & 31, ty = tid >> 5;

  // [c-quad][y 0..21][x 0..41][c%4]; x index = gx - (w0-4), window uses 1..38
  __shared__ float m_s[2][22][42][4];   // 29,568 B

  float acc0[49], acc1[49];
#pragma unroll
  for (int d = 0; d < 49; ++d) { acc0[d] = 0.f; acc1[d] = 0.f; }

  const int c8 = tid >> 5, st = tid & 31;   // staging map: 8 ch x 32 slots

#pragma unroll 1
  for (int cc = 0; cc < 8; ++cc) {          // 8-channel chunks
    __syncthreads();
    {
      const float* src = m_in + (((b * 64 + cc * 8 + c8) * 4 + t) << 14);
#pragma unroll
      for (int k = 0; k < 7; ++k) {         // 220 float4 per channel (22x10)
        const int p = st + 32 * k;
        if (p < 220) {
          const int y  = p / 10;            // magic-mul, ~3 instrs
          const int xf = p - y * 10;
          const int gy = h0 - 3 + y;
          const int gx = w0 - 4 + 4 * xf;   // 16B-aligned
          float4 v = make_float4(0.f, 0.f, 0.f, 0.f);
          if ((unsigned)gy < 128u && (unsigned)gx < 125u)
            v = *(const float4*)(src + (gy << 7) + gx);
          float* dp = &m_s[c8 >> 2][y][4 * xf][c8 & 3];
          dp[0] = v.x; dp[4] = v.y; dp[8] = v.z; dp[12] = v.w;
        }
      }
    }
    __syncthreads();

#pragma unroll
    for (int cq = 0; cq < 2; ++cq) {
      float q0[4], q1[4];
#pragma unroll
      for (int k = 0; k < 4; ++k) {
        const float* qp = q_in + ((b * 64 + cc * 8 + cq * 4 + k) << 14)
                        + ((h0 + 2 * ty) << 7) + w0 + tx;
        q0[k] = qp[0];
        q1[k] = qp[128];
      }
#pragma unroll
      for (int wr = 0; wr < 8; ++wr) {      // shared 8-row window
        const float4* rowp = (const float4*)&m_s[cq][2 * ty + wr][tx + 1][0];
#pragma unroll
        for (int dx = 0; dx < 7; ++dx) {
          const float4 mv = rowp[dx];
          if (wr < 7)
            acc0[wr * 7 + dx] += q0[0]*mv.x + q0[1]*mv.y + q0[2]*mv.z + q0[3]*mv.w;
          if (wr > 0)
            acc1[(wr - 1) * 7 + dx] += q1[0]*mv.x + q1[1]*mv.y + q1[2]*mv.z + q1[3]*mv.w;
        }
      }
    }
  }

  const int obase = ATTN_OFF + ((b * 196 + t) << 14)
                  + ((h0 + 2 * ty) << 7) + w0 + tx;
#pragma unroll
  for (int d = 0; d < 49; ++d) {
    out[obase +       ((d * 4) << 14)] = acc0[d];
    out[obase + 128 + ((d * 4) << 14)] = acc1[d];
  }
}

// ---------------------------------------------------------------------------
// K2: softmax (unchanged) + packed-attn write into d_ws.
// Packed layout keyed to k3's wave tiling: G = (h>>1)*4 + (w>>5),
// lane = (h&1)*32 + (w&31); element (b,G,t,g,lane) at
// ((b*256+G)*4+t)*13*64 + g*64 + lane   (float4 units, d = 4g+j).
// ---------------------------------------------------------------------------
__global__ __launch_bounds__(256) void k2_softmax(
    float* __restrict__ out, const float* __restrict__ cst,
    float4* __restrict__ ws)
{
  const int tid = threadIdx.x;
  const int pl = tid & 63;             // pixel within block
  const int t  = tid >> 6;
  const int pix = blockIdx.x * 64 + pl;      // 65536 pixels total
  const int b = pix >> 14, hw = pix & 16383;
  float* base = out + ATTN_OFF + ((b * 196 + t) << 14) + hw;

  float v[49];
#pragma unroll
  for (int d = 0; d < 49; ++d) v[d] = base[(d * 4) << 14];

  float mx = -1e30f;
#pragma unroll
  for (int d = 0; d < 49; ++d) mx = fmaxf(mx, v[d]);

  __shared__ float red[4][64];
  red[t][pl] = mx;
  __syncthreads();
  float M = fmaxf(fmaxf(red[0][pl], red[1][pl]), fmaxf(red[2][pl], red[3][pl]));
  M = fmaxf(M, cst[0]);
  __syncthreads();

  float s = 0.f;
#pragma unroll
  for (int d = 0; d < 49; ++d) { v[d] = __expf(v[d] - M); s += v[d]; }
  red[t][pl] = s;
  __syncthreads();
  const float l = red[0][pl] + red[1][pl] + red[2][pl] + red[3][pl]
                + __expf(cst[0] - M);
  const float inv = 1.f / l;
#pragma unroll
  for (int d = 0; d < 49; ++d) {
    const float r = v[d] * inv;
    base[(d * 4) << 14] = r;           // reference-layout output (validated)
    v[d] = r;
  }

  if (ws) {
    const int h = hw >> 7, wc = hw & 127;
    const int G    = ((h >> 1) << 2) + (wc >> 5);
    const int lane = ((h & 1) << 5) + (wc & 31);
    float4* dst = ws + (size_t)(((b * 256 + G) * 4 + t) * 13) * 64 + lane;
#pragma unroll
    for (int g = 0; g < 13; ++g) {
      float4 p;
      p.x = v[g * 4];
      p.y = (g < 12) ? v[g * 4 + 1] : 0.f;
      p.z = (g < 12) ? v[g * 4 + 2] : 0.f;
      p.w = (g < 12) ? v[g * 4 + 3] : 0.f;
      dst[g * 64] = p;
    }
  }
}

// ---------------------------------------------------------------------------
// K3 (packed-ws variant): attn read as 13 coalesced dwordx4 per (thread,t),
// 1-deep software pipeline. NEW: float4 division-free staging (same scheme as
// k1 v2), LDS x-dim padded to 42, reads at x = tx+dx+1. Tiling and ws layout
// unchanged.
// ---------------------------------------------------------------------------
__global__ __launch_bounds__(256) void k3_read_ws(
    const float* __restrict__ m_out, float* __restrict__ out,
    const float4* __restrict__ ws)
{
  const int b = blockIdx.z >> 2, cq = blockIdx.z & 3;
  const int h0 = blockIdx.y * 8, w0 = blockIdx.x * 32;
  const int tid = threadIdx.x;
  const int tx = tid & 31, ty = tid >> 5;
  const int h = h0 + ty, w = w0 + tx;
  const int waveid = tid >> 6, lane = tid & 63;
  const int G = ((h0 >> 1) + waveid) * 4 + blockIdx.x;

  __shared__ float m_s[4][14][42][4];  // 37,632 B

  float acc[16];
#pragma unroll
  for (int i = 0; i < 16; ++i) acc[i] = 0.f;

  const int c16 = tid >> 4, st = tid & 15;  // staging map: 16 ch x 16 slots

#pragma unroll 1
  for (int t = 0; t < 4; ++t) {
    const float4* ap = ws + (size_t)(((b * 256 + G) * 4 + t) * 13) * 64 + lane;

    __syncthreads();
    {
      const float* src = m_out + (((b * 64 + cq * 16 + c16) * 4 + t) << 14);
#pragma unroll
      for (int k = 0; k < 9; ++k) {        // 140 float4 per channel (14x10)
        const int p = st + 16 * k;
        if (p < 140) {
          const int y  = p / 10;
          const int xf = p - y * 10;
          const int gy = h0 - 3 + y;
          const int gx = w0 - 4 + 4 * xf;
          float4 v = make_float4(0.f, 0.f, 0.f, 0.f);
          if ((unsigned)gy < 128u && (unsigned)gx < 125u)
            v = *(const float4*)(src + (gy << 7) + gx);
          float* dp = &m_s[c16 >> 2][y][4 * xf][c16 & 3];
          dp[0] = v.x; dp[4] = v.y; dp[8] = v.z; dp[12] = v.w;
        }
      }
    }
    __syncthreads();

    float4 cur = ap[0];
#pragma unroll
    for (int g = 0; g < 13; ++g) {
      float4 nxt = cur;
      if (g < 12) nxt = ap[(g + 1) * 64];
#pragma unroll
      for (int j = 0; j < 4; ++j) {
        const int d = g * 4 + j;
        if (d >= 49) break;
        const int dy = d / 7, dx = d % 7;
        const float av = (j == 0) ? cur.x : (j == 1) ? cur.y
                       : (j == 2) ? cur.z : cur.w;
#pragma unroll
        for (int q = 0; q < 4; ++q) {
          const float4 mv = *(const float4*)&m_s[q][ty + dy][tx + dx + 1][0];
          acc[q * 4 + 0] += av * mv.x;
          acc[q * 4 + 1] += av * mv.y;
          acc[q * 4 + 2] += av * mv.z;
          acc[q * 4 + 3] += av * mv.w;
        }
      }
      cur = nxt;
    }
  }

#pragma unroll
  for (int q = 0; q < 4; ++q)
#pragma unroll
    for (int k = 0; k < 4; ++k)
      out[((b * 64 + cq * 16 + q * 4 + k) << 14) + (h << 7) + w] = acc[q * 4 + k];
}

// ---------------------------------------------------------------------------
// K3 fallback (unchanged) — used only if ws_size is too small.
// ---------------------------------------------------------------------------
__global__ __launch_bounds__(256) void k3_read_fb(
    const float* __restrict__ m_out, float* __restrict__ out)
{
  const int b = blockIdx.z >> 2, cq = blockIdx.z & 3;
  const int h0 = blockIdx.y * 8, w0 = blockIdx.x * 32;
  const int tid = threadIdx.x;
  const int tx = tid & 31, ty = tid >> 5;
  const int h = h0 + ty, w = w0 + tx;

  __shared__ float m_s[4][14][38][4];
  const float* __restrict__ attn = out + ATTN_OFF;

  float acc[16];
#pragma unroll
  for (int i = 0; i < 16; ++i) acc[i] = 0.f;

#pragma unroll 1
  for (int t = 0; t < 4; ++t) {
    float a[49];
#pragma unroll
    for (int d = 0; d < 49; ++d)
      a[d] = attn[((b * 196 + d * 4 + t) << 14) + (h << 7) + w];

    __syncthreads();
    for (int e = tid; e < 8512; e += 256) {
      int c16 = e / 532; int rem = e - c16 * 532;
      int y = rem / 38;  int x = rem - y * 38;
      int gy = h0 - 3 + y, gx = w0 - 3 + x;
      float v = 0.f;
      if (gy >= 0 && gy < 128 && gx >= 0 && gx < 128)
        v = m_out[(((b * 64 + cq * 16 + c16) * 4 + t) << 14) + (gy << 7) + gx];
      m_s[c16 >> 2][y][x][c16 & 3] = v;
    }
    __syncthreads();

#pragma unroll
    for (int dy = 0; dy < 7; ++dy)
#pragma unroll
      for (int dx = 0; dx < 7; ++dx) {
        const float av = a[dy * 7 + dx];
#pragma unroll
        for (int q = 0; q < 4; ++q) {
          const float4 mv = *(const float4*)&m_s[q][ty + dy][tx + dx][0];
          acc[q * 4 + 0] += av * mv.x;
          acc[q * 4 + 1] += av * mv.y;
          acc[q * 4 + 2] += av * mv.z;
          acc[q * 4 + 3] += av * mv.w;
        }
      }
  }

#pragma unroll
  for (int q = 0; q < 4; ++q)
#pragma unroll
    for (int k = 0; k < 4; ++k)
      out[((b * 64 + cq * 16 + q * 4 + k) << 14) + (h << 7) + w] = acc[q * 4 + k];
}

extern "C" void kernel_launch(void* const* d_in, const int* in_sizes, int n_in,
                              void* d_out, int out_size, void* d_ws, size_t ws_size,
                              hipStream_t stream) {
  const float* m_in  = (const float*)d_in[0];
  const float* m_out = (const float*)d_in[1];
  const float* q_in  = (const float*)d_in[2];
  const float* cst   = (const float*)d_in[3];
  float* out = (float*)d_out;

  const bool use_ws = (ws_size >= WS_F4_COUNT * 16ull) && d_ws != nullptr;
  float4* ws = use_ws ? (float4*)d_ws : nullptr;

  k1_corr<<<dim3(4, 8, 16), dim3(256), 0, stream>>>(m_in, q_in, out);
  k2_softmax<<<dim3(1024), dim3(256), 0, stream>>>(out, cst, ws);
  if (use_ws)
    k3_read_ws<<<dim3(4, 16, 16), dim3(256), 0, stream>>>(m_out, out, ws);
  else
    k3_read_fb<<<dim3(4, 16, 16), dim3(256), 0, stream>>>(m_out, out);
}